// Round 5
// baseline (617.931 us; speedup 1.0000x reference)
//
#include <hip/hip_runtime.h>
#include <hip/hip_bf16.h>

#define NN 2048
#define FIN 256
#define FOUT 256
#define HH 8

typedef __hip_bfloat16 bf16;

// dtype-agnostic input load (compile-time path)
template <int F32>
__device__ __forceinline__ float ldin(const void* p, long idx) {
    if (F32) return ((const float*)p)[idx];
    return __bfloat162float(((const bf16*)p)[idx]);
}

// ------------------------------------------------- K0: input dtype detection
// Little-endian f32: word 2k = LOW mantissa half (random -> wild as bf16),
// word 2k+1 = HIGH half (== truncated bf16, sane). Sample EVEN words.
__global__ void k0_detect(const void* __restrict__ x, const void* __restrict__ y,
                          int* __restrict__ flag) {
    __shared__ int wild;
    if (threadIdx.x == 0) wild = 0;
    __syncthreads();
    float a = __bfloat162float(((const bf16*)x)[2*threadIdx.x]);
    float b = __bfloat162float(((const bf16*)y)[2*threadIdx.x]);
    if (!(fabsf(a) < 1000.f) || !(fabsf(b) < 1000.f)) atomicAdd(&wild, 1);
    __syncthreads();
    if (threadIdx.x == 0) *flag = (wild > 0) ? 1 : 0;
}

// ---------------------------------------------------------------- K1: qk & v
template <int F32>
__device__ __forceinline__ void k1_body(
    const void* __restrict__ x, const void* __restrict__ Wq,
    const void* __restrict__ Wk, const void* __restrict__ Wv,
    float* __restrict__ v, float* __restrict__ qk)
{
    const int i = blockIdx.x;
    const int t = threadIdx.x;
    __shared__ float xs[FIN];
    __shared__ float part[64];
    xs[t] = ldin<F32>(x, (long)i*FIN + t);
    __syncthreads();
    float acc = 0.f;
    #pragma unroll 8
    for (int c = 0; c < FIN; ++c)
        acc = fmaf(xs[c], ldin<F32>(Wv, (long)c*FOUT + t), acc);
    v[i*FOUT + t] = acc * 0.0625f;
    if (t < 64) {
        const int h = t & 7, seg = t >> 3;
        float a = 0.f;
        for (int c = seg*32; c < seg*32 + 32; ++c)
            a = fmaf(xs[c], ldin<F32>(Wq, c*HH + h) + ldin<F32>(Wk, c*HH + h), a);
        part[t] = a;
    }
    __syncthreads();
    if (t < 8) {
        float a = 0.f;
        #pragma unroll
        for (int s2 = 0; s2 < 8; ++s2) a += part[s2*8 + t];
        qk[i*HH + t] = a * (0.0625f * 0.35355339059327373f); // *scale/sqrt(8)
    }
}
__global__ __launch_bounds__(256) void k1_qkv(
    const void* x, const void* Wq, const void* Wk, const void* Wv,
    float* v, float* qk, const int* __restrict__ dflag)
{
    if (*dflag) k1_body<1>(x, Wq, Wk, Wv, v, qk);
    else        k1_body<0>(x, Wq, Wk, Wv, v, qk);
}

// ------------------------------------------------- K2: column softmax denoms
// D[j,h] = sum_i [deg[i,j]>0] * exp(leaky_relu(qk[i,h] + s[i,j]))
template <int F32>
__device__ __forceinline__ void k2_body(
    const void* __restrict__ bond, const void* __restrict__ dist,
    const void* __restrict__ deg, const float* __restrict__ qk,
    float cb, float cg, float* __restrict__ D)
{
    const int tx = threadIdx.x & 63, ty = threadIdx.x >> 6;
    const int j  = blockIdx.x * 64 + tx;
    const int i0 = blockIdx.y * 128;
    __shared__ float qs[128*8];
    for (int p = threadIdx.x; p < 128*8; p += 256) qs[p] = qk[i0*8 + p];
    __syncthreads();
    float acc[8];
    #pragma unroll
    for (int h = 0; h < 8; ++h) acc[h] = 0.f;
    for (int ii = ty; ii < 128; ii += 4) {
        const long idx = (long)(i0 + ii)*NN + j;
        const float m = (ldin<F32>(deg, idx) > 0.f) ? 1.f : 0.f;
        const float s = fmaf(cb, ldin<F32>(bond, idx), cg * ldin<F32>(dist, idx));
        #pragma unroll
        for (int h = 0; h < 8; ++h) {
            float r = qs[ii*8 + h] + s;
            r = (r > 0.f) ? r : 0.2f*r;
            acc[h] += m * __expf(r);
        }
    }
    __shared__ float red[4][64][8];
    #pragma unroll
    for (int h = 0; h < 8; ++h) red[ty][tx][h] = acc[h];
    __syncthreads();
    for (int p = threadIdx.x; p < 512; p += 256) {
        const int jj = p >> 3, h = p & 7;
        const float ssum = red[0][jj][h] + red[1][jj][h] + red[2][jj][h] + red[3][jj][h];
        atomicAdd(&D[(blockIdx.x*64 + jj)*8 + h], ssum);
    }
}
__global__ __launch_bounds__(256) void k2_denom(
    const void* bond, const void* dist, const void* deg, const float* qk,
    const void* wb, const void* wbc, const void* wg, float* D,
    const int* __restrict__ dflag)
{
    if (*dflag) {
        const float cb = ldin<1>(wb,0) * ldin<1>(wbc,0), cg = ldin<1>(wg,0);
        k2_body<1>(bond, dist, deg, qk, cb, cg, D);
    } else {
        const float cb = ldin<0>(wb,0) * ldin<0>(wbc,0), cg = ldin<0>(wg,0);
        k2_body<0>(bond, dist, deg, qk, cb, cg, D);
    }
}

// ------------------------------------------------------------ K3: attn_mean
template <int F32>
__device__ __forceinline__ void k3_body(
    const void* __restrict__ bond, const void* __restrict__ dist,
    const void* __restrict__ deg, const float* __restrict__ qk,
    float cb, float cg, const float* __restrict__ D, float* __restrict__ am)
{
    const int tx = threadIdx.x & 63, ty = threadIdx.x >> 6;
    const int j  = blockIdx.x * 64 + tx;
    const int i0 = blockIdx.y * 128;
    __shared__ float qs[128*8];
    for (int p = threadIdx.x; p < 128*8; p += 256) qs[p] = qk[i0*8 + p];
    __syncthreads();
    float invD[8];
    #pragma unroll
    for (int h = 0; h < 8; ++h) invD[h] = 1.f / fmaxf(D[j*8 + h], 1e-30f);
    for (int ii = ty; ii < 128; ii += 4) {
        const long idx = (long)(i0 + ii)*NN + j;
        const float m = (ldin<F32>(deg, idx) > 0.f) ? 0.125f : 0.f;
        const float s = fmaf(cb, ldin<F32>(bond, idx), cg * ldin<F32>(dist, idx));
        float o = 0.f;
        #pragma unroll
        for (int h = 0; h < 8; ++h) {
            float r = qs[ii*8 + h] + s;
            r = (r > 0.f) ? r : 0.2f*r;
            o = fmaf(__expf(r), invD[h], o);
        }
        am[idx] = o * m;
    }
}
__global__ __launch_bounds__(256) void k3_attnmean(
    const void* bond, const void* dist, const void* deg, const float* qk,
    const void* wb, const void* wbc, const void* wg, const float* D,
    float* am, const int* __restrict__ dflag)
{
    if (*dflag) {
        const float cb = ldin<1>(wb,0) * ldin<1>(wbc,0), cg = ldin<1>(wg,0);
        k3_body<1>(bond, dist, deg, qk, cb, cg, D, am);
    } else {
        const float cb = ldin<0>(wb,0) * ldin<0>(wbc,0), cg = ldin<0>(wg,0);
        k3_body<0>(bond, dist, deg, qk, cb, cg, D, am);
    }
}

// --------------------- K4: aggregated = am @ v, elu -> un (fp32, = out0)
__global__ __launch_bounds__(256) void k4_aggr(
    const float* __restrict__ am, const float* __restrict__ v,
    float* __restrict__ un)
{
    const int i0 = blockIdx.x * 32;
    const int f0 = blockIdx.y * 64;
    const int t  = threadIdx.x;
    const int fc = t & 63;
    const int iw = t >> 6;           // 0..3
    __shared__ float As[32][33];
    __shared__ float Bs[32][64];
    float acc[8];
    #pragma unroll
    for (int r = 0; r < 8; ++r) acc[r] = 0.f;
    for (int kk = 0; kk < NN; kk += 32) {
        #pragma unroll
        for (int p = 0; p < 4; ++p) {
            const int lid = t + p*256;
            As[lid >> 5][lid & 31] = am[(long)(i0 + (lid >> 5))*NN + kk + (lid & 31)];
        }
        #pragma unroll
        for (int p = 0; p < 8; ++p) {
            const int lid = t + p*256;
            Bs[lid >> 6][lid & 63] = v[(kk + (lid >> 6))*FOUT + f0 + (lid & 63)];
        }
        __syncthreads();
        #pragma unroll
        for (int k2 = 0; k2 < 32; ++k2) {
            const float bv = Bs[k2][fc];
            #pragma unroll
            for (int r = 0; r < 8; ++r)
                acc[r] = fmaf(As[iw + r*4][k2], bv, acc[r]);
        }
        __syncthreads();
    }
    #pragma unroll
    for (int r = 0; r < 8; ++r) {
        const int i = i0 + iw + r*4;
        const float xv = acc[r];
        un[i*FOUT + f0 + fc] = (xv > 0.f) ? xv : (__expf(xv) - 1.f);
    }
}

// -------- K5: sim = un@un^T, conn0 = sigmoid(sim)*(-dist)*deg, + row stats
template <int F32>
__device__ __forceinline__ void k5_body(
    const float* __restrict__ un, const void* __restrict__ dist,
    const void* __restrict__ deg, float* __restrict__ c0,
    float* __restrict__ rowsum, float* __restrict__ rowsq)
{
    const int i0 = blockIdx.y * 64;
    const int j0 = blockIdx.x * 64;
    const int t  = threadIdx.x;
    const int tx = t & 15, ty = t >> 4;
    __shared__ float As[64][17];
    __shared__ float Bs[64][17];
    float acc[4][4];
    #pragma unroll
    for (int r = 0; r < 4; ++r)
        #pragma unroll
        for (int c = 0; c < 4; ++c) acc[r][c] = 0.f;
    for (int kk = 0; kk < FOUT; kk += 16) {
        #pragma unroll
        for (int p = 0; p < 4; ++p) {
            const int lid = t + p*256;
            const int r = lid >> 4, c = lid & 15;
            As[r][c] = un[(i0 + r)*FOUT + kk + c];
            Bs[r][c] = un[(j0 + r)*FOUT + kk + c];
        }
        __syncthreads();
        #pragma unroll
        for (int k2 = 0; k2 < 16; ++k2) {
            float a[4], b[4];
            #pragma unroll
            for (int r = 0; r < 4; ++r) a[r] = As[ty + 16*r][k2];
            #pragma unroll
            for (int c = 0; c < 4; ++c) b[c] = Bs[tx + 16*c][k2];
            #pragma unroll
            for (int r = 0; r < 4; ++r)
                #pragma unroll
                for (int c = 0; c < 4; ++c)
                    acc[r][c] = fmaf(a[r], b[c], acc[r][c]);
        }
        __syncthreads();
    }
    #pragma unroll
    for (int r = 0; r < 4; ++r) {
        const int i = i0 + ty + 16*r;
        float srow = 0.f, qrow = 0.f;
        #pragma unroll
        for (int c = 0; c < 4; ++c) {
            const int j = j0 + tx + 16*c;
            const long idx = (long)i*NN + j;
            const float sg = 1.f / (1.f + __expf(-acc[r][c]));
            const float val = sg * (-ldin<F32>(dist, idx)) * ldin<F32>(deg, idx);
            c0[idx] = val;
            srow += val;
            qrow = fmaf(val, val, qrow);
        }
        #pragma unroll
        for (int off = 8; off > 0; off >>= 1) {
            srow += __shfl_down(srow, off, 16);
            qrow += __shfl_down(qrow, off, 16);
        }
        if (tx == 0) {
            atomicAdd(&rowsum[i], srow);
            atomicAdd(&rowsq[i],  qrow);
        }
    }
}
__global__ __launch_bounds__(256) void k5_sim(
    const float* un, const void* dist, const void* deg, float* c0,
    float* rowsum, float* rowsq, const int* __restrict__ dflag)
{
    if (*dflag) k5_body<1>(un, dist, deg, c0, rowsum, rowsq);
    else        k5_body<0>(un, dist, deg, c0, rowsum, rowsq);
}

// ------------------------------------------------------------- K6: mu / rstd
__global__ void k6_stats(const float* __restrict__ rowsum,
                         const float* __restrict__ rowsq,
                         float* __restrict__ mu, float* __restrict__ rs)
{
    const int i = blockIdx.x*256 + threadIdx.x;
    if (i < NN) {
        const float m = rowsum[i] * (1.f/NN);
        const float var = rowsq[i] * (1.f/NN) - m*m;
        mu[i] = m;
        rs[i] = rsqrtf(var + 1e-5f);
    }
}

// ---------------------------- K7: conn = norm(c0) + norm(c0)^T -> fp32 output
__global__ __launch_bounds__(256) void k7_conn(
    const float* __restrict__ c0, const float* __restrict__ mu,
    const float* __restrict__ rs, float* __restrict__ out1)
{
    const int i0 = blockIdx.y * 64;
    const int j0 = blockIdx.x * 64;
    const int t  = threadIdx.x;
    __shared__ float L[64][65];
    #pragma unroll
    for (int p = 0; p < 16; ++p) {
        const int lid = t + p*256;
        const int a = lid >> 6, b = lid & 63;
        L[a][b] = c0[(long)(j0 + a)*NN + i0 + b];   // tile of c0[j, i]
    }
    __syncthreads();
    #pragma unroll
    for (int p = 0; p < 16; ++p) {
        const int lid = t + p*256;
        const int rr = lid >> 6, cc = lid & 63;
        const int i = i0 + rr, j = j0 + cc;
        const float x  = c0[(long)i*NN + j];
        const float xt = L[cc][rr];           // c0[j, i]
        out1[(long)i*NN + j] = (x - mu[i])*rs[i] + (xt - mu[j])*rs[j];
    }
}

extern "C" void kernel_launch(void* const* d_in, const int* in_sizes, int n_in,
                              void* d_out, int out_size, void* d_ws, size_t ws_size,
                              hipStream_t stream)
{
    const void* x    = d_in[0];
    const void* dist = d_in[1];
    const void* bond = d_in[2];
    // d_in[3] edge_direction: unused (only l=0 component couples; Y_0 = 1)
    const void* deg  = d_in[4];
    const void* Wq   = d_in[5];
    const void* Wk   = d_in[6];
    const void* Wv   = d_in[7];
    const void* wb   = d_in[8];
    const void* wbc  = d_in[9];
    const void* wg   = d_in[10];

    float* out0 = (float*)d_out;            // updated_nodes: 2048*256 fp32
    float* out1 = out0 + (size_t)NN*FOUT;   // conn: 2048*2048 fp32

    // Workspace layout (disjoint! R4 had qk overlapping v -> garbage):
    //   am     @ 0         size 16,777,216  (N*N f32; reused as conn0)
    //   v      @ 16777216  size  2,097,152  (N*F f32)
    //   qk     @ 18874368  size     65,536  (N*8 f32)
    //   D      @ 18939904  size     65,536  (N*8 f32)
    //   rowsum @ 19005440  size      8,192
    //   rowsq  @ 19013632  size      8,192
    //   mu     @ 19021824  size      8,192
    //   rs     @ 19030016  size      8,192
    //   dflag  @ 19038208  size          4
    char* w = (char*)d_ws;
    float* am     = (float*)(w);
    float* v      = (float*)(w + 16777216);
    float* qk     = (float*)(w + 18874368);
    float* D      = (float*)(w + 18939904);
    float* rowsum = (float*)(w + 19005440);
    float* rowsq  = (float*)(w + 19013632);
    float* mu     = (float*)(w + 19021824);
    float* rs     = (float*)(w + 19030016);
    int*   dflag  = (int*)  (w + 19038208);

    k0_detect<<<1, 256, 0, stream>>>(x, dist, dflag);
    // zero the accumulators (D, rowsum, rowsq are contiguous)
    hipMemsetAsync(D, 0, 65536 + 8192 + 8192, stream);

    k1_qkv<<<NN, 256, 0, stream>>>(x, Wq, Wk, Wv, v, qk, dflag);
    dim3 g23(NN/64, NN/128);
    k2_denom<<<g23, 256, 0, stream>>>(bond, dist, deg, qk, wb, wbc, wg, D, dflag);
    k3_attnmean<<<g23, 256, 0, stream>>>(bond, dist, deg, qk, wb, wbc, wg, D, am, dflag);
    dim3 g4(NN/32, FOUT/64);
    k4_aggr<<<g4, 256, 0, stream>>>(am, v, out0 /* un */);
    dim3 g5(NN/64, NN/64);
    k5_sim<<<g5, 256, 0, stream>>>(out0 /* un */, dist, deg, am /*conn0*/, rowsum, rowsq, dflag);
    k6_stats<<<8, 256, 0, stream>>>(rowsum, rowsq, mu, rs);
    k7_conn<<<g5, 256, 0, stream>>>(am, mu, rs, out1);
}

// Round 6
// 319.600 us; speedup vs baseline: 1.9335x; 1.9335x over previous
//
#include <hip/hip_runtime.h>
#include <hip/hip_bf16.h>

#define NN 2048
#define FIN 256
#define FOUT 256
#define HH 8

typedef __hip_bfloat16 bf16;

// dtype-agnostic input load (compile-time path)
template <int F32>
__device__ __forceinline__ float ldin(const void* p, long idx) {
    if (F32) return ((const float*)p)[idx];
    return __bfloat162float(((const bf16*)p)[idx]);
}

// ------------------------------------------------- K0: input dtype detection
// Little-endian f32: word 2k = LOW mantissa half (random -> wild as bf16),
// word 2k+1 = HIGH half (== truncated bf16, sane). Sample EVEN words.
__global__ void k0_detect(const void* __restrict__ x, const void* __restrict__ y,
                          int* __restrict__ flag) {
    __shared__ int wild;
    if (threadIdx.x == 0) wild = 0;
    __syncthreads();
    float a = __bfloat162float(((const bf16*)x)[2*threadIdx.x]);
    float b = __bfloat162float(((const bf16*)y)[2*threadIdx.x]);
    if (!(fabsf(a) < 1000.f) || !(fabsf(b) < 1000.f)) atomicAdd(&wild, 1);
    __syncthreads();
    if (threadIdx.x == 0) *flag = (wild > 0) ? 1 : 0;
}

// ---------------------------------------------------------------- K1: qk & v
template <int F32>
__device__ __forceinline__ void k1_body(
    const void* __restrict__ x, const void* __restrict__ Wq,
    const void* __restrict__ Wk, const void* __restrict__ Wv,
    float* __restrict__ v, float* __restrict__ qk)
{
    const int i = blockIdx.x;
    const int t = threadIdx.x;
    __shared__ float xs[FIN];
    __shared__ float part[64];
    xs[t] = ldin<F32>(x, (long)i*FIN + t);
    __syncthreads();
    float acc = 0.f;
    #pragma unroll 8
    for (int c = 0; c < FIN; ++c)
        acc = fmaf(xs[c], ldin<F32>(Wv, (long)c*FOUT + t), acc);
    v[i*FOUT + t] = acc * 0.0625f;
    if (t < 64) {
        const int h = t & 7, seg = t >> 3;
        float a = 0.f;
        for (int c = seg*32; c < seg*32 + 32; ++c)
            a = fmaf(xs[c], ldin<F32>(Wq, c*HH + h) + ldin<F32>(Wk, c*HH + h), a);
        part[t] = a;
    }
    __syncthreads();
    if (t < 8) {
        float a = 0.f;
        #pragma unroll
        for (int s2 = 0; s2 < 8; ++s2) a += part[s2*8 + t];
        qk[i*HH + t] = a * (0.0625f * 0.35355339059327373f); // *scale/sqrt(8)
    }
}
__global__ __launch_bounds__(256) void k1_qkv(
    const void* x, const void* Wq, const void* Wk, const void* Wv,
    float* v, float* qk, const int* __restrict__ dflag)
{
    if (*dflag) k1_body<1>(x, Wq, Wk, Wv, v, qk);
    else        k1_body<0>(x, Wq, Wk, Wv, v, qk);
}

// ------------------------------------------------- K2: column softmax denoms
// D[j,h] = sum_i [deg[i,j]>0] * exp(leaky_relu(qk[i,h] + s[i,j]))
template <int F32>
__device__ __forceinline__ void k2_body(
    const void* __restrict__ bond, const void* __restrict__ dist,
    const void* __restrict__ deg, const float* __restrict__ qk,
    float cb, float cg, float* __restrict__ D)
{
    const int tx = threadIdx.x & 63, ty = threadIdx.x >> 6;
    const int j  = blockIdx.x * 64 + tx;
    const int i0 = blockIdx.y * 128;
    __shared__ float qs[128*8];
    for (int p = threadIdx.x; p < 128*8; p += 256) qs[p] = qk[i0*8 + p];
    __syncthreads();
    float acc[8];
    #pragma unroll
    for (int h = 0; h < 8; ++h) acc[h] = 0.f;
    for (int ii = ty; ii < 128; ii += 4) {
        const long idx = (long)(i0 + ii)*NN + j;
        const float m = (ldin<F32>(deg, idx) > 0.f) ? 1.f : 0.f;
        const float s = fmaf(cb, ldin<F32>(bond, idx), cg * ldin<F32>(dist, idx));
        #pragma unroll
        for (int h = 0; h < 8; ++h) {
            float r = qs[ii*8 + h] + s;
            r = (r > 0.f) ? r : 0.2f*r;
            acc[h] += m * __expf(r);
        }
    }
    __shared__ float red[4][64][8];
    #pragma unroll
    for (int h = 0; h < 8; ++h) red[ty][tx][h] = acc[h];
    __syncthreads();
    for (int p = threadIdx.x; p < 512; p += 256) {
        const int jj = p >> 3, h = p & 7;
        const float ssum = red[0][jj][h] + red[1][jj][h] + red[2][jj][h] + red[3][jj][h];
        atomicAdd(&D[(blockIdx.x*64 + jj)*8 + h], ssum);
    }
}
__global__ __launch_bounds__(256) void k2_denom(
    const void* bond, const void* dist, const void* deg, const float* qk,
    const void* wb, const void* wbc, const void* wg, float* D,
    const int* __restrict__ dflag)
{
    if (*dflag) {
        const float cb = ldin<1>(wb,0) * ldin<1>(wbc,0), cg = ldin<1>(wg,0);
        k2_body<1>(bond, dist, deg, qk, cb, cg, D);
    } else {
        const float cb = ldin<0>(wb,0) * ldin<0>(wbc,0), cg = ldin<0>(wg,0);
        k2_body<0>(bond, dist, deg, qk, cb, cg, D);
    }
}

// ------------------------------------------------------------ K3: attn_mean
template <int F32>
__device__ __forceinline__ void k3_body(
    const void* __restrict__ bond, const void* __restrict__ dist,
    const void* __restrict__ deg, const float* __restrict__ qk,
    float cb, float cg, const float* __restrict__ D, float* __restrict__ am)
{
    const int tx = threadIdx.x & 63, ty = threadIdx.x >> 6;
    const int j  = blockIdx.x * 64 + tx;
    const int i0 = blockIdx.y * 128;
    __shared__ float qs[128*8];
    for (int p = threadIdx.x; p < 128*8; p += 256) qs[p] = qk[i0*8 + p];
    __syncthreads();
    float invD[8];
    #pragma unroll
    for (int h = 0; h < 8; ++h) invD[h] = 1.f / fmaxf(D[j*8 + h], 1e-30f);
    for (int ii = ty; ii < 128; ii += 4) {
        const long idx = (long)(i0 + ii)*NN + j;
        const float m = (ldin<F32>(deg, idx) > 0.f) ? 0.125f : 0.f;
        const float s = fmaf(cb, ldin<F32>(bond, idx), cg * ldin<F32>(dist, idx));
        float o = 0.f;
        #pragma unroll
        for (int h = 0; h < 8; ++h) {
            float r = qs[ii*8 + h] + s;
            r = (r > 0.f) ? r : 0.2f*r;
            o = fmaf(__expf(r), invD[h], o);
        }
        am[idx] = o * m;
    }
}
__global__ __launch_bounds__(256) void k3_attnmean(
    const void* bond, const void* dist, const void* deg, const float* qk,
    const void* wb, const void* wbc, const void* wg, const float* D,
    float* am, const int* __restrict__ dflag)
{
    if (*dflag) {
        const float cb = ldin<1>(wb,0) * ldin<1>(wbc,0), cg = ldin<1>(wg,0);
        k3_body<1>(bond, dist, deg, qk, cb, cg, D, am);
    } else {
        const float cb = ldin<0>(wb,0) * ldin<0>(wbc,0), cg = ldin<0>(wg,0);
        k3_body<0>(bond, dist, deg, qk, cb, cg, D, am);
    }
}

// --------------------- K4: aggregated += am @ v (K-split, atomic accumulate)
// grid (32 i-tiles, 4 f-tiles, 4 k-splits) = 512 blocks; 64x64 tile, 4x4/thread.
// agg (= out0) must be pre-zeroed.
__global__ __launch_bounds__(256) void k4_aggr(
    const float* __restrict__ am, const float* __restrict__ v,
    float* __restrict__ agg)
{
    const int i0 = blockIdx.x * 64;
    const int f0 = blockIdx.y * 64;
    const int k0 = blockIdx.z * 512;
    const int t  = threadIdx.x;
    const int tx = t & 15, ty = t >> 4;
    __shared__ float Ast[16][68];   // [k][row]  (68: b128-aligned + conflict-free)
    __shared__ float Bs [16][68];   // [k][col]
    float acc[4][4];
    #pragma unroll
    for (int r = 0; r < 4; ++r)
        #pragma unroll
        for (int c = 0; c < 4; ++c) acc[r][c] = 0.f;

    const int lr = t >> 2;          // 0..63: am row for staging
    const int lc = (t & 3) * 4;     // k-quad
    const int vr = t >> 4;          // 0..15: v row for staging
    const int vc = (t & 15) * 4;    // col-quad

    for (int kk = k0; kk < k0 + 512; kk += 16) {
        const float4 a4 = *(const float4*)&am[(long)(i0 + lr)*NN + kk + lc];
        const float4 b4 = *(const float4*)&v[(kk + vr)*FOUT + f0 + vc];
        Ast[lc+0][lr] = a4.x; Ast[lc+1][lr] = a4.y;
        Ast[lc+2][lr] = a4.z; Ast[lc+3][lr] = a4.w;
        *(float4*)&Bs[vr][vc] = b4;
        __syncthreads();
        #pragma unroll
        for (int k2 = 0; k2 < 16; ++k2) {
            const float4 av = *(const float4*)&Ast[k2][ty*4];
            const float4 bv = *(const float4*)&Bs[k2][tx*4];
            const float a[4] = {av.x, av.y, av.z, av.w};
            const float b[4] = {bv.x, bv.y, bv.z, bv.w};
            #pragma unroll
            for (int r = 0; r < 4; ++r)
                #pragma unroll
                for (int c = 0; c < 4; ++c)
                    acc[r][c] = fmaf(a[r], b[c], acc[r][c]);
        }
        __syncthreads();
    }
    #pragma unroll
    for (int r = 0; r < 4; ++r)
        #pragma unroll
        for (int c = 0; c < 4; ++c)
            atomicAdd(&agg[(i0 + ty*4 + r)*FOUT + f0 + tx*4 + c], acc[r][c]);
}

// ------------------------------- K4b: elu in place (agg -> un, un lives in out0)
__global__ __launch_bounds__(256) void k4b_elu(float* __restrict__ un)
{
    const int idx = blockIdx.x*256 + threadIdx.x;   // float4 index
    float4* p = (float4*)un;
    float4 vv = p[idx];
    vv.x = (vv.x > 0.f) ? vv.x : (__expf(vv.x) - 1.f);
    vv.y = (vv.y > 0.f) ? vv.y : (__expf(vv.y) - 1.f);
    vv.z = (vv.z > 0.f) ? vv.z : (__expf(vv.z) - 1.f);
    vv.w = (vv.w > 0.f) ? vv.w : (__expf(vv.w) - 1.f);
    p[idx] = vv;
}

// -------- K5: sim = un@un^T, conn0 = sigmoid(sim)*(-dist)*deg, + row stats
template <int F32>
__device__ __forceinline__ void k5_body(
    const float* __restrict__ un, const void* __restrict__ dist,
    const void* __restrict__ deg, float* __restrict__ c0,
    float* __restrict__ rowsum, float* __restrict__ rowsq)
{
    const int i0 = blockIdx.y * 64;
    const int j0 = blockIdx.x * 64;
    const int t  = threadIdx.x;
    const int tx = t & 15, ty = t >> 4;
    __shared__ float As[64][17];
    __shared__ float Bs[64][17];
    float acc[4][4];
    #pragma unroll
    for (int r = 0; r < 4; ++r)
        #pragma unroll
        for (int c = 0; c < 4; ++c) acc[r][c] = 0.f;
    for (int kk = 0; kk < FOUT; kk += 16) {
        #pragma unroll
        for (int p = 0; p < 4; ++p) {
            const int lid = t + p*256;
            const int r = lid >> 4, c = lid & 15;
            As[r][c] = un[(i0 + r)*FOUT + kk + c];
            Bs[r][c] = un[(j0 + r)*FOUT + kk + c];
        }
        __syncthreads();
        #pragma unroll
        for (int k2 = 0; k2 < 16; ++k2) {
            float a[4], b[4];
            #pragma unroll
            for (int r = 0; r < 4; ++r) a[r] = As[ty + 16*r][k2];
            #pragma unroll
            for (int c = 0; c < 4; ++c) b[c] = Bs[tx + 16*c][k2];
            #pragma unroll
            for (int r = 0; r < 4; ++r)
                #pragma unroll
                for (int c = 0; c < 4; ++c)
                    acc[r][c] = fmaf(a[r], b[c], acc[r][c]);
        }
        __syncthreads();
    }
    #pragma unroll
    for (int r = 0; r < 4; ++r) {
        const int i = i0 + ty + 16*r;
        float srow = 0.f, qrow = 0.f;
        #pragma unroll
        for (int c = 0; c < 4; ++c) {
            const int j = j0 + tx + 16*c;
            const long idx = (long)i*NN + j;
            const float sg = 1.f / (1.f + __expf(-acc[r][c]));
            const float val = sg * (-ldin<F32>(dist, idx)) * ldin<F32>(deg, idx);
            c0[idx] = val;
            srow += val;
            qrow = fmaf(val, val, qrow);
        }
        #pragma unroll
        for (int off = 8; off > 0; off >>= 1) {
            srow += __shfl_down(srow, off, 16);
            qrow += __shfl_down(qrow, off, 16);
        }
        if (tx == 0) {
            atomicAdd(&rowsum[i], srow);
            atomicAdd(&rowsq[i],  qrow);
        }
    }
}
__global__ __launch_bounds__(256) void k5_sim(
    const float* un, const void* dist, const void* deg, float* c0,
    float* rowsum, float* rowsq, const int* __restrict__ dflag)
{
    if (*dflag) k5_body<1>(un, dist, deg, c0, rowsum, rowsq);
    else        k5_body<0>(un, dist, deg, c0, rowsum, rowsq);
}

// ------------------------------------------------------------- K6: mu / rstd
__global__ void k6_stats(const float* __restrict__ rowsum,
                         const float* __restrict__ rowsq,
                         float* __restrict__ mu, float* __restrict__ rs)
{
    const int i = blockIdx.x*256 + threadIdx.x;
    if (i < NN) {
        const float m = rowsum[i] * (1.f/NN);
        const float var = rowsq[i] * (1.f/NN) - m*m;
        mu[i] = m;
        rs[i] = rsqrtf(var + 1e-5f);
    }
}

// ---------------------------- K7: conn = norm(c0) + norm(c0)^T -> fp32 output
__global__ __launch_bounds__(256) void k7_conn(
    const float* __restrict__ c0, const float* __restrict__ mu,
    const float* __restrict__ rs, float* __restrict__ out1)
{
    const int i0 = blockIdx.y * 64;
    const int j0 = blockIdx.x * 64;
    const int t  = threadIdx.x;
    __shared__ float L[64][65];
    #pragma unroll
    for (int p = 0; p < 16; ++p) {
        const int lid = t + p*256;
        const int a = lid >> 6, b = lid & 63;
        L[a][b] = c0[(long)(j0 + a)*NN + i0 + b];   // tile of c0[j, i]
    }
    __syncthreads();
    #pragma unroll
    for (int p = 0; p < 16; ++p) {
        const int lid = t + p*256;
        const int rr = lid >> 6, cc = lid & 63;
        const int i = i0 + rr, j = j0 + cc;
        const float x  = c0[(long)i*NN + j];
        const float xt = L[cc][rr];           // c0[j, i]
        out1[(long)i*NN + j] = (x - mu[i])*rs[i] + (xt - mu[j])*rs[j];
    }
}

extern "C" void kernel_launch(void* const* d_in, const int* in_sizes, int n_in,
                              void* d_out, int out_size, void* d_ws, size_t ws_size,
                              hipStream_t stream)
{
    const void* x    = d_in[0];
    const void* dist = d_in[1];
    const void* bond = d_in[2];
    // d_in[3] edge_direction: unused (only l=0 component couples; Y_0 = 1)
    const void* deg  = d_in[4];
    const void* Wq   = d_in[5];
    const void* Wk   = d_in[6];
    const void* Wv   = d_in[7];
    const void* wb   = d_in[8];
    const void* wbc  = d_in[9];
    const void* wg   = d_in[10];

    float* out0 = (float*)d_out;            // updated_nodes: 2048*256 fp32
    float* out1 = out0 + (size_t)NN*FOUT;   // conn: 2048*2048 fp32

    // Workspace layout (disjoint!):
    char* w = (char*)d_ws;
    float* am     = (float*)(w);                 // 16,777,216 B (N*N; reused as conn0)
    float* v      = (float*)(w + 16777216);      //  2,097,152 B
    float* qk     = (float*)(w + 18874368);      //     65,536 B
    float* D      = (float*)(w + 18939904);      //     65,536 B
    float* rowsum = (float*)(w + 19005440);      //      8,192 B
    float* rowsq  = (float*)(w + 19013632);      //      8,192 B
    float* mu     = (float*)(w + 19021824);      //      8,192 B
    float* rs     = (float*)(w + 19030016);      //      8,192 B
    int*   dflag  = (int*)  (w + 19038208);      //          4 B

    k0_detect<<<1, 256, 0, stream>>>(x, dist, dflag);
    // zero accumulators: D/rowsum/rowsq (contiguous) + out0 (k4 atomic target)
    hipMemsetAsync(D, 0, 65536 + 8192 + 8192, stream);
    hipMemsetAsync(out0, 0, (size_t)NN*FOUT*4, stream);

    k1_qkv<<<NN, 256, 0, stream>>>(x, Wq, Wk, Wv, v, qk, dflag);
    dim3 g23(NN/64, NN/128);
    k2_denom<<<g23, 256, 0, stream>>>(bond, dist, deg, qk, wb, wbc, wg, D, dflag);
    k3_attnmean<<<g23, 256, 0, stream>>>(bond, dist, deg, qk, wb, wbc, wg, D, am, dflag);
    dim3 g4(NN/64, FOUT/64, 4);
    k4_aggr<<<g4, 256, 0, stream>>>(am, v, out0);
    k4b_elu<<<NN*FOUT/4/256, 256, 0, stream>>>(out0);
    dim3 g5(NN/64, NN/64);
    k5_sim<<<g5, 256, 0, stream>>>(out0 /* un */, dist, deg, am /*conn0*/, rowsum, rowsq, dflag);
    k6_stats<<<8, 256, 0, stream>>>(rowsum, rowsq, mu, rs);
    k7_conn<<<g5, 256, 0, stream>>>(am, mu, rs, out1);
}

// Round 7
// 266.994 us; speedup vs baseline: 2.3144x; 1.1970x over previous
//
#include <hip/hip_runtime.h>
#include <hip/hip_bf16.h>

#define NN 2048
#define FIN 256
#define FOUT 256
#define HH 8

// ---------------------------------------------------------------- K1: qk & v
// 2 nodes per block; Wv streamed once per block (L2-resident), 1024 blocks.
__global__ __launch_bounds__(256) void k1_qkv(
    const float* __restrict__ x, const float* __restrict__ Wq,
    const float* __restrict__ Wk, const float* __restrict__ Wv,
    float* __restrict__ v, float* __restrict__ qk)
{
    const int ib = blockIdx.x * 2;
    const int t  = threadIdx.x;
    __shared__ float xs[2][FIN];
    __shared__ float part[128];
    xs[0][t] = x[(long)ib*FIN + t];
    xs[1][t] = x[(long)(ib+1)*FIN + t];
    __syncthreads();
    float a0 = 0.f, a1 = 0.f;
    #pragma unroll 8
    for (int c = 0; c < FIN; ++c) {
        const float w = Wv[c*FOUT + t];
        a0 = fmaf(xs[0][c], w, a0);
        a1 = fmaf(xs[1][c], w, a1);
    }
    v[ib*FOUT + t]     = a0 * 0.0625f;
    v[(ib+1)*FOUT + t] = a1 * 0.0625f;
    if (t < 128) {                      // qk for both nodes: n=t>>6, h=t&7, seg=(t>>3)&7
        const int n = t >> 6, h = t & 7, seg = (t >> 3) & 7;
        float a = 0.f;
        for (int c = seg*32; c < seg*32 + 32; ++c)
            a = fmaf(xs[n][c], Wq[c*HH + h] + Wk[c*HH + h], a);
        part[t] = a;
    }
    __syncthreads();
    if (t < 16) {
        const int n = t >> 3, h = t & 7;
        float a = 0.f;
        #pragma unroll
        for (int s2 = 0; s2 < 8; ++s2) a += part[n*64 + s2*8 + h];
        qk[(ib+n)*HH + h] = a * (0.0625f * 0.35355339059327373f); // *scale/sqrt(8)
    }
}

// ------------------------------------------------- K2: column softmax denoms
// D[j,h] = sum_i [deg[i,j]>0] * exp(leaky_relu(qk[i,h] + s[i,j]))
__global__ __launch_bounds__(256) void k2_denom(
    const float* __restrict__ bond, const float* __restrict__ dist,
    const float* __restrict__ deg, const float* __restrict__ qk,
    const float* __restrict__ wb, const float* __restrict__ wbc,
    const float* __restrict__ wg, float* __restrict__ D)
{
    const float cb = wb[0] * wbc[0];
    const float cg = wg[0];
    const int tx = threadIdx.x & 63, ty = threadIdx.x >> 6;
    const int j  = blockIdx.x * 64 + tx;
    const int i0 = blockIdx.y * 128;
    __shared__ float qs[128*8];
    for (int p = threadIdx.x; p < 128*8; p += 256) qs[p] = qk[i0*8 + p];
    __syncthreads();
    float acc[8];
    #pragma unroll
    for (int h = 0; h < 8; ++h) acc[h] = 0.f;
    for (int ii = ty; ii < 128; ii += 4) {
        const long idx = (long)(i0 + ii)*NN + j;
        const float m = (deg[idx] > 0.f) ? 1.f : 0.f;
        const float s = fmaf(cb, bond[idx], cg * dist[idx]);
        #pragma unroll
        for (int h = 0; h < 8; ++h) {
            float r = qs[ii*8 + h] + s;
            r = (r > 0.f) ? r : 0.2f*r;
            acc[h] += m * __expf(r);
        }
    }
    __shared__ float red[4][64][8];
    #pragma unroll
    for (int h = 0; h < 8; ++h) red[ty][tx][h] = acc[h];
    __syncthreads();
    for (int p = threadIdx.x; p < 512; p += 256) {
        const int jj = p >> 3, h = p & 7;
        const float ssum = red[0][jj][h] + red[1][jj][h] + red[2][jj][h] + red[3][jj][h];
        atomicAdd(&D[(blockIdx.x*64 + jj)*8 + h], ssum);
    }
}

// ------------------------------------------------------------ K3: attn_mean
__global__ __launch_bounds__(256) void k3_attnmean(
    const float* __restrict__ bond, const float* __restrict__ dist,
    const float* __restrict__ deg, const float* __restrict__ qk,
    const float* __restrict__ wb, const float* __restrict__ wbc,
    const float* __restrict__ wg, const float* __restrict__ D,
    float* __restrict__ am)
{
    const float cb = wb[0] * wbc[0];
    const float cg = wg[0];
    const int tx = threadIdx.x & 63, ty = threadIdx.x >> 6;
    const int j  = blockIdx.x * 64 + tx;
    const int i0 = blockIdx.y * 128;
    __shared__ float qs[128*8];
    for (int p = threadIdx.x; p < 128*8; p += 256) qs[p] = qk[i0*8 + p];
    __syncthreads();
    float invD[8];
    #pragma unroll
    for (int h = 0; h < 8; ++h) invD[h] = 1.f / fmaxf(D[j*8 + h], 1e-30f);
    for (int ii = ty; ii < 128; ii += 4) {
        const long idx = (long)(i0 + ii)*NN + j;
        const float m = (deg[idx] > 0.f) ? 0.125f : 0.f;
        const float s = fmaf(cb, bond[idx], cg * dist[idx]);
        float o = 0.f;
        #pragma unroll
        for (int h = 0; h < 8; ++h) {
            float r = qs[ii*8 + h] + s;
            r = (r > 0.f) ? r : 0.2f*r;
            o = fmaf(__expf(r), invD[h], o);
        }
        am[idx] = o * m;
    }
}

// --------------- K4: partial[z] = am(:, z-slice) @ v(z-slice, :)  (no atomics)
// grid (32 i-tiles, 4 f-tiles, 8 k-splits); 64x64 tile, 4x4/thread, b128 LDS.
__global__ __launch_bounds__(256) void k4_aggr(
    const float* __restrict__ am, const float* __restrict__ v,
    float* __restrict__ partial)
{
    const int i0 = blockIdx.x * 64;
    const int f0 = blockIdx.y * 64;
    const int k0 = blockIdx.z * 256;
    const int t  = threadIdx.x;
    const int tx = t & 15, ty = t >> 4;
    __shared__ float Ast[16][68];   // [k][row]
    __shared__ float Bs [16][68];   // [k][col]
    float acc[4][4];
    #pragma unroll
    for (int r = 0; r < 4; ++r)
        #pragma unroll
        for (int c = 0; c < 4; ++c) acc[r][c] = 0.f;

    const int lr = t >> 2;          // 0..63: tile row
    const int lc = (t & 3) * 4;     // k-quad
    const int vr = t >> 4;          // 0..15: k row for v staging
    const int vc = (t & 15) * 4;    // col-quad

    for (int kk = k0; kk < k0 + 256; kk += 16) {
        const float4 a4 = *(const float4*)&am[(long)(i0 + lr)*NN + kk + lc];
        const float4 b4 = *(const float4*)&v[(kk + vr)*FOUT + f0 + vc];
        Ast[lc+0][lr] = a4.x; Ast[lc+1][lr] = a4.y;
        Ast[lc+2][lr] = a4.z; Ast[lc+3][lr] = a4.w;
        *(float4*)&Bs[vr][vc] = b4;
        __syncthreads();
        #pragma unroll
        for (int k2 = 0; k2 < 16; ++k2) {
            const float4 av = *(const float4*)&Ast[k2][ty*4];
            const float4 bv = *(const float4*)&Bs[k2][tx*4];
            const float a[4] = {av.x, av.y, av.z, av.w};
            const float b[4] = {bv.x, bv.y, bv.z, bv.w};
            #pragma unroll
            for (int r = 0; r < 4; ++r)
                #pragma unroll
                for (int c = 0; c < 4; ++c)
                    acc[r][c] = fmaf(a[r], b[c], acc[r][c]);
        }
        __syncthreads();
    }
    float* out = partial + (long)blockIdx.z * NN * FOUT;
    #pragma unroll
    for (int r = 0; r < 4; ++r)
        *(float4*)&out[(i0 + ty*4 + r)*FOUT + f0 + tx*4] = *(float4*)&acc[r][0];
}

// ------------------- K4b: sum 8 partials + elu -> un (fp32, lives in out0)
__global__ __launch_bounds__(256) void k4b_elu(
    const float* __restrict__ partial, float* __restrict__ un)
{
    const int idx = blockIdx.x*256 + threadIdx.x;   // float4 index
    const float4* p = (const float4*)partial;
    float4 s = p[idx];
    #pragma unroll
    for (int z = 1; z < 8; ++z) {
        const float4 q = p[idx + z*(NN*FOUT/4)];
        s.x += q.x; s.y += q.y; s.z += q.z; s.w += q.w;
    }
    s.x = (s.x > 0.f) ? s.x : (__expf(s.x) - 1.f);
    s.y = (s.y > 0.f) ? s.y : (__expf(s.y) - 1.f);
    s.z = (s.z > 0.f) ? s.z : (__expf(s.z) - 1.f);
    s.w = (s.w > 0.f) ? s.w : (__expf(s.w) - 1.f);
    ((float4*)un)[idx] = s;
}

// -------- K5: sim = un@un^T, conn0 = sigmoid(sim)*(-dist)*deg, + row stats
__global__ __launch_bounds__(256) void k5_sim(
    const float* __restrict__ un, const float* __restrict__ dist,
    const float* __restrict__ deg, float* __restrict__ c0,
    float* __restrict__ rowsum, float* __restrict__ rowsq)
{
    const int i0 = blockIdx.y * 64;
    const int j0 = blockIdx.x * 64;
    const int t  = threadIdx.x;
    const int tx = t & 15, ty = t >> 4;
    __shared__ float As[16][68];    // [k][row]
    __shared__ float Bs[16][68];    // [k][col]
    float acc[4][4];
    #pragma unroll
    for (int r = 0; r < 4; ++r)
        #pragma unroll
        for (int c = 0; c < 4; ++c) acc[r][c] = 0.f;

    const int lr = t >> 2;          // 0..63
    const int lc = (t & 3) * 4;     // k-quad

    for (int kk = 0; kk < FOUT; kk += 16) {
        const float4 a4 = *(const float4*)&un[(i0 + lr)*FOUT + kk + lc];
        const float4 b4 = *(const float4*)&un[(j0 + lr)*FOUT + kk + lc];
        As[lc+0][lr] = a4.x; As[lc+1][lr] = a4.y;
        As[lc+2][lr] = a4.z; As[lc+3][lr] = a4.w;
        Bs[lc+0][lr] = b4.x; Bs[lc+1][lr] = b4.y;
        Bs[lc+2][lr] = b4.z; Bs[lc+3][lr] = b4.w;
        __syncthreads();
        #pragma unroll
        for (int k2 = 0; k2 < 16; ++k2) {
            const float4 av = *(const float4*)&As[k2][ty*4];
            const float4 bv = *(const float4*)&Bs[k2][tx*4];
            const float a[4] = {av.x, av.y, av.z, av.w};
            const float b[4] = {bv.x, bv.y, bv.z, bv.w};
            #pragma unroll
            for (int r = 0; r < 4; ++r)
                #pragma unroll
                for (int c = 0; c < 4; ++c)
                    acc[r][c] = fmaf(a[r], b[c], acc[r][c]);
        }
        __syncthreads();
    }
    #pragma unroll
    for (int r = 0; r < 4; ++r) {
        const int i = i0 + ty*4 + r;
        const long rb = (long)i*NN + j0 + tx*4;
        const float4 d4 = *(const float4*)&dist[rb];
        const float4 g4 = *(const float4*)&deg[rb];
        const float dd[4] = {d4.x, d4.y, d4.z, d4.w};
        const float gg[4] = {g4.x, g4.y, g4.z, g4.w};
        float val[4];
        float srow = 0.f, qrow = 0.f;
        #pragma unroll
        for (int c = 0; c < 4; ++c) {
            const float sg = 1.f / (1.f + __expf(-acc[r][c]));
            val[c] = sg * (-dd[c]) * gg[c];
            srow += val[c];
            qrow = fmaf(val[c], val[c], qrow);
        }
        *(float4*)&c0[rb] = *(float4*)&val[0];
        #pragma unroll
        for (int off = 8; off > 0; off >>= 1) {
            srow += __shfl_down(srow, off, 16);
            qrow += __shfl_down(qrow, off, 16);
        }
        if (tx == 0) {
            atomicAdd(&rowsum[i], srow);
            atomicAdd(&rowsq[i],  qrow);
        }
    }
}

// ------------------------------------------------------------- K6: mu / rstd
__global__ void k6_stats(const float* __restrict__ rowsum,
                         const float* __restrict__ rowsq,
                         float* __restrict__ mu, float* __restrict__ rs)
{
    const int i = blockIdx.x*256 + threadIdx.x;
    if (i < NN) {
        const float m = rowsum[i] * (1.f/NN);
        const float var = rowsq[i] * (1.f/NN) - m*m;
        mu[i] = m;
        rs[i] = rsqrtf(var + 1e-5f);
    }
}

// ---------------------------- K7: conn = norm(c0) + norm(c0)^T -> fp32 output
__global__ __launch_bounds__(256) void k7_conn(
    const float* __restrict__ c0, const float* __restrict__ mu,
    const float* __restrict__ rs, float* __restrict__ out1)
{
    const int i0 = blockIdx.y * 64;
    const int j0 = blockIdx.x * 64;
    const int t  = threadIdx.x;
    __shared__ float L[64][65];
    #pragma unroll
    for (int p = 0; p < 16; ++p) {
        const int lid = t + p*256;
        const int a = lid >> 6, b = lid & 63;
        L[a][b] = c0[(long)(j0 + a)*NN + i0 + b];   // tile of c0[j, i]
    }
    __syncthreads();
    #pragma unroll
    for (int p = 0; p < 16; ++p) {
        const int lid = t + p*256;
        const int rr = lid >> 6, cc = lid & 63;
        const int i = i0 + rr, j = j0 + cc;
        const float x  = c0[(long)i*NN + j];
        const float xt = L[cc][rr];           // c0[j, i]
        out1[(long)i*NN + j] = (x - mu[i])*rs[i] + (xt - mu[j])*rs[j];
    }
}

extern "C" void kernel_launch(void* const* d_in, const int* in_sizes, int n_in,
                              void* d_out, int out_size, void* d_ws, size_t ws_size,
                              hipStream_t stream)
{
    // Inputs are float32 (proven: rounds 1/2 bf16-misread -> NaN; round 3
    // signature 4.750021 = bf16-written-fp32-read of conn). Outputs fp32.
    const float* x    = (const float*)d_in[0];
    const float* dist = (const float*)d_in[1];
    const float* bond = (const float*)d_in[2];
    // d_in[3] edge_direction: unused (only l=0 component couples; Y_0 = 1)
    const float* deg  = (const float*)d_in[4];
    const float* Wq   = (const float*)d_in[5];
    const float* Wk   = (const float*)d_in[6];
    const float* Wv   = (const float*)d_in[7];
    const float* wb   = (const float*)d_in[8];
    const float* wbc  = (const float*)d_in[9];
    const float* wg   = (const float*)d_in[10];

    float* out0 = (float*)d_out;            // updated_nodes: 2048*256 fp32
    float* out1 = out0 + (size_t)NN*FOUT;   // conn: 2048*2048 fp32

    // Workspace layout (disjoint):
    char* w = (char*)d_ws;
    float* am      = (float*)(w);                 // 16,777,216 B (N*N; reused as conn0)
    float* partial = (float*)(w + 16777216);      // 16,777,216 B (8 x N*F)
    float* v       = (float*)(w + 33554432);      //  2,097,152 B
    float* qk      = (float*)(w + 35651584);      //     65,536 B
    float* D       = (float*)(w + 35717120);      //     65,536 B
    float* rowsum  = (float*)(w + 35782656);      //      8,192 B
    float* rowsq   = (float*)(w + 35790848);      //      8,192 B
    float* mu      = (float*)(w + 35799040);      //      8,192 B
    float* rs      = (float*)(w + 35807232);      //      8,192 B

    // zero the accumulators (D, rowsum, rowsq are contiguous)
    hipMemsetAsync(D, 0, 65536 + 8192 + 8192, stream);

    k1_qkv<<<NN/2, 256, 0, stream>>>(x, Wq, Wk, Wv, v, qk);
    dim3 g23(NN/64, NN/128);
    k2_denom<<<g23, 256, 0, stream>>>(bond, dist, deg, qk, wb, wbc, wg, D);
    k3_attnmean<<<g23, 256, 0, stream>>>(bond, dist, deg, qk, wb, wbc, wg, D, am);
    dim3 g4(NN/64, FOUT/64, 8);
    k4_aggr<<<g4, 256, 0, stream>>>(am, v, partial);
    k4b_elu<<<NN*FOUT/4/256, 256, 0, stream>>>(partial, out0);
    dim3 g5(NN/64, NN/64);
    k5_sim<<<g5, 256, 0, stream>>>(out0 /* un */, dist, deg, am /*conn0*/, rowsum, rowsq);
    k6_stats<<<8, 256, 0, stream>>>(rowsum, rowsq, mu, rs);
    k7_conn<<<g5, 256, 0, stream>>>(am, mu, rs, out1);
}

// Round 8
// 260.191 us; speedup vs baseline: 2.3749x; 1.0261x over previous
//
#include <hip/hip_runtime.h>
#include <hip/hip_bf16.h>

#define NN 2048
#define FIN 256
#define FOUT 256
#define HH 8

typedef short bhalf8 __attribute__((ext_vector_type(8)));   // 8 bf16 (4 VGPRs)
typedef float f32x4  __attribute__((ext_vector_type(4)));   // MFMA acc

__device__ __forceinline__ unsigned short f2b(float f) {
    __hip_bfloat16 h = __float2bfloat16(f);
    return *reinterpret_cast<unsigned short*>(&h);
}
__device__ __forceinline__ float b2f(unsigned short u) {
    __hip_bfloat16 h = *reinterpret_cast<__hip_bfloat16*>(&u);
    return __bfloat162float(h);
}

// ---------------------------------------------------------------- K1: qk & v
// 4 nodes per block (4 FMA per Wv load); Wv is L2/L3-resident across blocks.
__global__ __launch_bounds__(256) void k1_qkv(
    const float* __restrict__ x, const float* __restrict__ Wq,
    const float* __restrict__ Wk, const float* __restrict__ Wv,
    float* __restrict__ v, float* __restrict__ qk)
{
    const int ib = blockIdx.x * 4;
    const int t  = threadIdx.x;
    __shared__ float xs[4][FIN];
    __shared__ float part[256];
    #pragma unroll
    for (int n = 0; n < 4; ++n) xs[n][t] = x[(long)(ib+n)*FIN + t];
    __syncthreads();
    float a0 = 0.f, a1 = 0.f, a2 = 0.f, a3 = 0.f;
    #pragma unroll 4
    for (int c = 0; c < FIN; ++c) {
        const float wv = Wv[c*FOUT + t];
        a0 = fmaf(xs[0][c], wv, a0); a1 = fmaf(xs[1][c], wv, a1);
        a2 = fmaf(xs[2][c], wv, a2); a3 = fmaf(xs[3][c], wv, a3);
    }
    v[(ib+0)*FOUT + t] = a0 * 0.0625f;
    v[(ib+1)*FOUT + t] = a1 * 0.0625f;
    v[(ib+2)*FOUT + t] = a2 * 0.0625f;
    v[(ib+3)*FOUT + t] = a3 * 0.0625f;
    {   // qk: n=t>>6, h=t&7, seg=(t>>3)&7  (256 threads cover 4 nodes x 8 h x 8 seg)
        const int n = t >> 6, h = t & 7, seg = (t >> 3) & 7;
        float a = 0.f;
        for (int c = seg*32; c < seg*32 + 32; ++c)
            a = fmaf(xs[n][c], Wq[c*HH + h] + Wk[c*HH + h], a);
        part[t] = a;
    }
    __syncthreads();
    if (t < 32) {
        const int n = t >> 3, h = t & 7;
        float a = 0.f;
        #pragma unroll
        for (int s2 = 0; s2 < 8; ++s2) a += part[n*64 + s2*8 + h];
        qk[(ib+n)*HH + h] = a * (0.0625f * 0.35355339059327373f); // *scale/sqrt(8)
    }
}

// ------------------------------- K1b: vT_bf16[f][k] = bf16(v[k][f])  (1 MB)
__global__ __launch_bounds__(256) void k1b_vT(
    const float* __restrict__ v, unsigned short* __restrict__ vtb)
{
    const int k0 = blockIdx.x * 64;   // 32 k-tiles
    const int f0 = blockIdx.y * 64;   // 4 f-tiles
    const int t  = threadIdx.x;
    __shared__ float LT[64][68];      // LT[f_local][k_local]
    const int r  = t >> 4;            // 16 rows per pass
    const int c4 = (t & 15) * 4;
    #pragma unroll
    for (int p = 0; p < 4; ++p) {
        const float4 q = *(const float4*)&v[(k0 + r + p*16)*FOUT + f0 + c4];
        LT[c4+0][r + p*16] = q.x; LT[c4+1][r + p*16] = q.y;
        LT[c4+2][r + p*16] = q.z; LT[c4+3][r + p*16] = q.w;
    }
    __syncthreads();
    #pragma unroll
    for (int p = 0; p < 4; ++p) {
        const int fr = r + p*16;
        ushort4 ub;
        ub.x = f2b(LT[fr][c4+0]); ub.y = f2b(LT[fr][c4+1]);
        ub.z = f2b(LT[fr][c4+2]); ub.w = f2b(LT[fr][c4+3]);
        *(ushort4*)&vtb[(long)(f0 + fr)*NN + k0 + c4] = ub;
    }
}

// ------------------------------------------------- K2: denoms + f-field
// f[i,j] = masked ? -inf : cb*bond+cg*dist (bf16);  D[j,h] = sum_i exp(leaky(qk+f))
__global__ __launch_bounds__(256) void k2_denom(
    const float* __restrict__ bond, const float* __restrict__ dist,
    const float* __restrict__ deg, const float* __restrict__ qk,
    const float* __restrict__ wb, const float* __restrict__ wbc,
    const float* __restrict__ wg, float* __restrict__ D,
    unsigned short* __restrict__ fbuf)
{
    const float cb = wb[0] * wbc[0];
    const float cg = wg[0];
    const int tx = threadIdx.x & 63, ty = threadIdx.x >> 6;
    const int j  = blockIdx.x * 64 + tx;
    const int i0 = blockIdx.y * 128;
    __shared__ float qs[128*8];
    for (int p = threadIdx.x; p < 128*8; p += 256) qs[p] = qk[i0*8 + p];
    __syncthreads();
    float acc[8];
    #pragma unroll
    for (int h = 0; h < 8; ++h) acc[h] = 0.f;
    for (int ii = ty; ii < 128; ii += 4) {
        const long idx = (long)(i0 + ii)*NN + j;
        const float s0 = fmaf(cb, bond[idx], cg * dist[idx]);
        const unsigned short fb = f2b((deg[idx] > 0.f) ? s0 : -__builtin_inff());
        fbuf[idx] = fb;
        const float s = b2f(fb);            // use rounded value: consistent w/ k3
        #pragma unroll
        for (int h = 0; h < 8; ++h) {
            float r = qs[ii*8 + h] + s;
            r = (r > 0.f) ? r : 0.2f*r;
            acc[h] += __expf(r);            // masked: exp(-inf) = 0
        }
    }
    __shared__ float red[4][64][8];
    #pragma unroll
    for (int h = 0; h < 8; ++h) red[ty][tx][h] = acc[h];
    __syncthreads();
    for (int p = threadIdx.x; p < 512; p += 256) {
        const int jj = p >> 3, h = p & 7;
        const float ssum = red[0][jj][h] + red[1][jj][h] + red[2][jj][h] + red[3][jj][h];
        atomicAdd(&D[(blockIdx.x*64 + jj)*8 + h], ssum);
    }
}

// --------------------------- K3: attn_mean -> bf16  (reads only f-field + qk/D)
__global__ __launch_bounds__(256) void k3_attnmean(
    const unsigned short* __restrict__ fbuf, const float* __restrict__ qk,
    const float* __restrict__ D, unsigned short* __restrict__ amb)
{
    const int tx = threadIdx.x & 63, ty = threadIdx.x >> 6;
    const int j  = blockIdx.x * 64 + tx;
    const int i0 = blockIdx.y * 128;
    __shared__ float qs[128*8];
    for (int p = threadIdx.x; p < 128*8; p += 256) qs[p] = qk[i0*8 + p];
    __syncthreads();
    float invD[8];
    #pragma unroll
    for (int h = 0; h < 8; ++h) invD[h] = 0.125f / fmaxf(D[j*8 + h], 1e-30f);
    for (int ii = ty; ii < 128; ii += 4) {
        const long idx = (long)(i0 + ii)*NN + j;
        const float s = b2f(fbuf[idx]);
        float o = 0.f;
        #pragma unroll
        for (int h = 0; h < 8; ++h) {
            float r = qs[ii*8 + h] + s;
            r = (r > 0.f) ? r : 0.2f*r;
            o = fmaf(__expf(r), invD[h], o);   // masked: exp(-inf)=0 -> o=0
        }
        amb[idx] = f2b(o);
    }
}

// --------------- K4: partial[z] = am_bf(:, z) @ vT_bf(z, :)^T via MFMA
// grid (32 i-tiles, 4 f-tiles, 4 z). Both fragments are row-reads (A.B^T form).
__global__ __launch_bounds__(256) void k4_aggr(
    const unsigned short* __restrict__ amb,
    const unsigned short* __restrict__ vtb, float* __restrict__ partial)
{
    const int i0 = blockIdx.x * 64;
    const int f0 = blockIdx.y * 64;
    const int k0 = blockIdx.z * 512;
    const int w  = threadIdx.x >> 6;      // wave 0..3
    const int l  = threadIdx.x & 63;
    const int lm = l & 15, lq = l >> 4;
    const int iw = i0 + w*16;
    f32x4 acc[4] = {f32x4{0,0,0,0}, f32x4{0,0,0,0}, f32x4{0,0,0,0}, f32x4{0,0,0,0}};
    for (int kk = k0; kk < k0 + 512; kk += 32) {
        const bhalf8 a = *(const bhalf8*)&amb[(long)(iw + lm)*NN + kk + lq*8];
        #pragma unroll
        for (int c = 0; c < 4; ++c) {
            const bhalf8 b = *(const bhalf8*)&vtb[(long)(f0 + c*16 + lm)*NN + kk + lq*8];
            acc[c] = __builtin_amdgcn_mfma_f32_16x16x32_bf16(a, b, acc[c], 0, 0, 0);
        }
    }
    float* out = partial + (long)blockIdx.z * NN * FOUT;
    #pragma unroll
    for (int c = 0; c < 4; ++c)
        #pragma unroll
        for (int r = 0; r < 4; ++r)
            out[(iw + lq*4 + r)*FOUT + f0 + c*16 + lm] = acc[c][r];
}

// ---------------- K4b: sum 4 partials + elu -> out0 (fp32) + un_bf16
__global__ __launch_bounds__(256) void k4b_elu(
    const float* __restrict__ partial, float* __restrict__ un,
    unsigned short* __restrict__ unb)
{
    const int idx = blockIdx.x*256 + threadIdx.x;   // float4 index
    const float4* p = (const float4*)partial;
    float4 s = p[idx];
    #pragma unroll
    for (int z = 1; z < 4; ++z) {
        const float4 q = p[idx + z*(NN*FOUT/4)];
        s.x += q.x; s.y += q.y; s.z += q.z; s.w += q.w;
    }
    s.x = (s.x > 0.f) ? s.x : (__expf(s.x) - 1.f);
    s.y = (s.y > 0.f) ? s.y : (__expf(s.y) - 1.f);
    s.z = (s.z > 0.f) ? s.z : (__expf(s.z) - 1.f);
    s.w = (s.w > 0.f) ? s.w : (__expf(s.w) - 1.f);
    ((float4*)un)[idx] = s;
    ushort4 ub; ub.x = f2b(s.x); ub.y = f2b(s.y); ub.z = f2b(s.z); ub.w = f2b(s.w);
    *(ushort4*)&unb[(long)idx*4] = ub;
}

// -------- K5: sim = un@un^T via MFMA; conn0 = sigmoid(sim)*(-dist)*deg; stats
__global__ __launch_bounds__(256) void k5_sim(
    const unsigned short* __restrict__ unb, const float* __restrict__ dist,
    const float* __restrict__ deg, float* __restrict__ c0,
    float* __restrict__ rowsum, float* __restrict__ rowsq)
{
    const int i0 = blockIdx.y * 64;
    const int j0 = blockIdx.x * 64;
    const int w  = threadIdx.x >> 6;
    const int l  = threadIdx.x & 63;
    const int lm = l & 15, lq = l >> 4;
    const int iw = i0 + w*16;
    f32x4 acc[4] = {f32x4{0,0,0,0}, f32x4{0,0,0,0}, f32x4{0,0,0,0}, f32x4{0,0,0,0}};
    for (int kk = 0; kk < FOUT; kk += 32) {
        const bhalf8 a = *(const bhalf8*)&unb[(long)(iw + lm)*FOUT + kk + lq*8];
        #pragma unroll
        for (int c = 0; c < 4; ++c) {
            const bhalf8 b = *(const bhalf8*)&unb[(long)(j0 + c*16 + lm)*FOUT + kk + lq*8];
            acc[c] = __builtin_amdgcn_mfma_f32_16x16x32_bf16(a, b, acc[c], 0, 0, 0);
        }
    }
    float srow[4] = {0.f,0.f,0.f,0.f}, qrow[4] = {0.f,0.f,0.f,0.f};
    #pragma unroll
    for (int c = 0; c < 4; ++c) {
        #pragma unroll
        for (int r = 0; r < 4; ++r) {
            const int i = iw + lq*4 + r;                 // C/D: row=(l>>4)*4+reg
            const int j = j0 + c*16 + lm;                //      col=l&15
            const long idx = (long)i*NN + j;
            const float sg = 1.f / (1.f + __expf(-acc[c][r]));
            const float val = sg * (-dist[idx]) * deg[idx];
            c0[idx] = val;
            srow[r] += val;
            qrow[r] = fmaf(val, val, qrow[r]);
        }
    }
    #pragma unroll
    for (int r = 0; r < 4; ++r) {
        #pragma unroll
        for (int m = 8; m >= 1; m >>= 1) {
            srow[r] += __shfl_xor(srow[r], m, 64);
            qrow[r] += __shfl_xor(qrow[r], m, 64);
        }
        if (lm == 0) {
            atomicAdd(&rowsum[iw + lq*4 + r], srow[r]);
            atomicAdd(&rowsq[iw + lq*4 + r],  qrow[r]);
        }
    }
}

// ------------------------------------------------------------- K6: mu / rstd
__global__ void k6_stats(const float* __restrict__ rowsum,
                         const float* __restrict__ rowsq,
                         float* __restrict__ mu, float* __restrict__ rs)
{
    const int i = blockIdx.x*256 + threadIdx.x;
    if (i < NN) {
        const float m = rowsum[i] * (1.f/NN);
        const float var = rowsq[i] * (1.f/NN) - m*m;
        mu[i] = m;
        rs[i] = rsqrtf(var + 1e-5f);
    }
}

// ---------------------------- K7: conn = norm(c0) + norm(c0)^T (float4 both ways)
__global__ __launch_bounds__(256) void k7_conn(
    const float* __restrict__ c0, const float* __restrict__ mu,
    const float* __restrict__ rs, float* __restrict__ out1)
{
    const int i0 = blockIdx.y * 64;
    const int j0 = blockIdx.x * 64;
    const int t  = threadIdx.x;
    __shared__ float LT[64][68];     // LT[i_local][j_local] = c0[j0+jl][i0+il]
    __shared__ float muj[64], rsj[64];
    const int r  = t >> 4;           // 16 rows per pass
    const int c4 = (t & 15) * 4;
    if (t < 64)        muj[t] = mu[j0 + t];
    else if (t < 128)  rsj[t-64] = rs[j0 + t - 64];
    #pragma unroll
    for (int p = 0; p < 4; ++p) {
        const int jl = r + p*16;
        const float4 q = *(const float4*)&c0[(long)(j0 + jl)*NN + i0 + c4];
        LT[c4+0][jl] = q.x; LT[c4+1][jl] = q.y;
        LT[c4+2][jl] = q.z; LT[c4+3][jl] = q.w;
    }
    __syncthreads();
    #pragma unroll
    for (int p = 0; p < 4; ++p) {
        const int rr = r + p*16;
        const int i  = i0 + rr;
        const float4 x = *(const float4*)&c0[(long)i*NN + j0 + c4];
        const float4 xt = *(const float4*)&LT[rr][c4];
        const float mi = mu[i], ri = rs[i];
        float4 o;
        o.x = (x.x - mi)*ri + (xt.x - muj[c4+0])*rsj[c4+0];
        o.y = (x.y - mi)*ri + (xt.y - muj[c4+1])*rsj[c4+1];
        o.z = (x.z - mi)*ri + (xt.z - muj[c4+2])*rsj[c4+2];
        o.w = (x.w - mi)*ri + (xt.w - muj[c4+3])*rsj[c4+3];
        *(float4*)&out1[(long)i*NN + j0 + c4] = o;
    }
}

extern "C" void kernel_launch(void* const* d_in, const int* in_sizes, int n_in,
                              void* d_out, int out_size, void* d_ws, size_t ws_size,
                              hipStream_t stream)
{
    // Inputs fp32, outputs fp32 (established rounds 1-5).
    const float* x    = (const float*)d_in[0];
    const float* dist = (const float*)d_in[1];
    const float* bond = (const float*)d_in[2];
    // d_in[3] edge_direction: unused (only l=0 component couples; Y_0 = 1)
    const float* deg  = (const float*)d_in[4];
    const float* Wq   = (const float*)d_in[5];
    const float* Wk   = (const float*)d_in[6];
    const float* Wv   = (const float*)d_in[7];
    const float* wb   = (const float*)d_in[8];
    const float* wbc  = (const float*)d_in[9];
    const float* wg   = (const float*)d_in[10];

    float* out0 = (float*)d_out;            // updated_nodes: 2048*256 fp32
    float* out1 = out0 + (size_t)NN*FOUT;   // conn: 2048*2048 fp32

    // Workspace (~29.5 MB). Deliberate reuse: c0 spans [0,16.8MB) on top of
    // fbuf [0,8.4M) and amb [8.4M,16.8M). Lifetimes: fbuf dead after k3,
    // amb dead after k4; c0 first written in k5. No overlap in time.
    char* w = (char*)d_ws;
    unsigned short* fbuf = (unsigned short*)(w);              // 8,388,608 B
    unsigned short* amb  = (unsigned short*)(w + 8388608);    // 8,388,608 B
    float* c0      = (float*)(w);                             // 16,777,216 B (after k4)
    float* partial = (float*)(w + 16777216);                  // 8,388,608 B (4 z)
    float* v       = (float*)(w + 25165824);                  // 2,097,152 B
    unsigned short* vtb = (unsigned short*)(w + 27262976);    // 1,048,576 B
    unsigned short* unb = (unsigned short*)(w + 28311552);    // 1,048,576 B
    float* qk      = (float*)(w + 29360128);                  // 65,536 B
    float* D       = (float*)(w + 29425664);                  // 65,536 B
    float* rowsum  = (float*)(w + 29491200);                  // 8,192 B
    float* rowsq   = (float*)(w + 29499392);                  // 8,192 B
    float* mu      = (float*)(w + 29507584);                  // 8,192 B
    float* rs      = (float*)(w + 29515776);                  // 8,192 B

    // zero accumulators (D, rowsum, rowsq contiguous)
    hipMemsetAsync(D, 0, 65536 + 8192 + 8192, stream);

    k1_qkv<<<NN/4, 256, 0, stream>>>(x, Wq, Wk, Wv, v, qk);
    dim3 g1b(NN/64, FOUT/64);
    k1b_vT<<<g1b, 256, 0, stream>>>(v, vtb);
    dim3 g23(NN/64, NN/128);
    k2_denom<<<g23, 256, 0, stream>>>(bond, dist, deg, qk, wb, wbc, wg, D, fbuf);
    k3_attnmean<<<g23, 256, 0, stream>>>(fbuf, qk, D, amb);
    dim3 g4(NN/64, FOUT/64, 4);
    k4_aggr<<<g4, 256, 0, stream>>>(amb, vtb, partial);
    k4b_elu<<<NN*FOUT/4/256, 256, 0, stream>>>(partial, out0, unb);
    dim3 g5(NN/64, NN/64);
    k5_sim<<<g5, 256, 0, stream>>>(unb, dist, deg, c0, rowsum, rowsq);
    k6_stats<<<8, 256, 0, stream>>>(rowsum, rowsq, mu, rs);
    k7_conn<<<g5, 256, 0, stream>>>(c0, mu, rs, out1);
}

// Round 9
// 243.090 us; speedup vs baseline: 2.5420x; 1.0703x over previous
//
#include <hip/hip_runtime.h>
#include <hip/hip_bf16.h>

#define NN 2048
#define FIN 256
#define FOUT 256
#define HH 8

typedef short bhalf8 __attribute__((ext_vector_type(8)));   // 8 bf16 (4 VGPRs)
typedef float f32x4  __attribute__((ext_vector_type(4)));   // MFMA acc

__device__ __forceinline__ unsigned short f2b(float f) {
    __hip_bfloat16 h = __float2bfloat16(f);
    return *reinterpret_cast<unsigned short*>(&h);
}
__device__ __forceinline__ float b2f(unsigned short u) {
    __hip_bfloat16 h = *reinterpret_cast<__hip_bfloat16*>(&u);
    return __bfloat162float(h);
}

// ---------------------------------------------------------------- K1: qk & v
// 4 nodes per block; Wv L2-resident across blocks.
__global__ __launch_bounds__(256) void k1_qkv(
    const float* __restrict__ x, const float* __restrict__ Wq,
    const float* __restrict__ Wk, const float* __restrict__ Wv,
    float* __restrict__ v, float* __restrict__ qk)
{
    const int ib = blockIdx.x * 4;
    const int t  = threadIdx.x;
    __shared__ float xs[4][FIN];
    __shared__ float part[256];
    #pragma unroll
    for (int n = 0; n < 4; ++n) xs[n][t] = x[(long)(ib+n)*FIN + t];
    __syncthreads();
    float a0 = 0.f, a1 = 0.f, a2 = 0.f, a3 = 0.f;
    #pragma unroll 4
    for (int c = 0; c < FIN; ++c) {
        const float wv = Wv[c*FOUT + t];
        a0 = fmaf(xs[0][c], wv, a0); a1 = fmaf(xs[1][c], wv, a1);
        a2 = fmaf(xs[2][c], wv, a2); a3 = fmaf(xs[3][c], wv, a3);
    }
    v[(ib+0)*FOUT + t] = a0 * 0.0625f;
    v[(ib+1)*FOUT + t] = a1 * 0.0625f;
    v[(ib+2)*FOUT + t] = a2 * 0.0625f;
    v[(ib+3)*FOUT + t] = a3 * 0.0625f;
    {
        const int n = t >> 6, h = t & 7, seg = (t >> 3) & 7;
        float a = 0.f;
        for (int c = seg*32; c < seg*32 + 32; ++c)
            a = fmaf(xs[n][c], Wq[c*HH + h] + Wk[c*HH + h], a);
        part[t] = a;
    }
    __syncthreads();
    if (t < 32) {
        const int n = t >> 3, h = t & 7;
        float a = 0.f;
        #pragma unroll
        for (int s2 = 0; s2 < 8; ++s2) a += part[n*64 + s2*8 + h];
        qk[(ib+n)*HH + h] = a * (0.0625f * 0.35355339059327373f); // *scale/sqrt(8)
    }
}

// ------------------------------- K1b: vT_bf16[f][k] = bf16(v[k][f])  (1 MB)
__global__ __launch_bounds__(256) void k1b_vT(
    const float* __restrict__ v, unsigned short* __restrict__ vtb)
{
    const int k0 = blockIdx.x * 64;
    const int f0 = blockIdx.y * 64;
    const int t  = threadIdx.x;
    __shared__ float LT[64][68];
    const int r  = t >> 4;
    const int c4 = (t & 15) * 4;
    #pragma unroll
    for (int p = 0; p < 4; ++p) {
        const float4 q = *(const float4*)&v[(k0 + r + p*16)*FOUT + f0 + c4];
        LT[c4+0][r + p*16] = q.x; LT[c4+1][r + p*16] = q.y;
        LT[c4+2][r + p*16] = q.z; LT[c4+3][r + p*16] = q.w;
    }
    __syncthreads();
    #pragma unroll
    for (int p = 0; p < 4; ++p) {
        const int fr = r + p*16;
        ushort4 ub;
        ub.x = f2b(LT[fr][c4+0]); ub.y = f2b(LT[fr][c4+1]);
        ub.z = f2b(LT[fr][c4+2]); ub.w = f2b(LT[fr][c4+3]);
        *(ushort4*)&vtb[(long)(f0 + fr)*NN + k0 + c4] = ub;
    }
}

// ------------------------------------------------- K2: denoms + f-field + dd
// f[i,j] = masked ? -inf : cb*bond+cg*dist (bf16);  ddb[i,j] = bf16(-dist*deg)
// D[j,h] = sum_i exp(leaky(qk[i,h] + f[i,j]))
__global__ __launch_bounds__(256) void k2_denom(
    const float* __restrict__ bond, const float* __restrict__ dist,
    const float* __restrict__ deg, const float* __restrict__ qk,
    const float* __restrict__ wb, const float* __restrict__ wbc,
    const float* __restrict__ wg, float* __restrict__ D,
    unsigned short* __restrict__ fbuf, unsigned short* __restrict__ ddb)
{
    const float cb = wb[0] * wbc[0];
    const float cg = wg[0];
    const int tx = threadIdx.x & 63, ty = threadIdx.x >> 6;
    const int j  = blockIdx.x * 64 + tx;
    const int i0 = blockIdx.y * 64;
    __shared__ float qs[64*8];
    for (int p = threadIdx.x; p < 64*8; p += 256) qs[p] = qk[i0*8 + p];
    __syncthreads();
    float acc[8];
    #pragma unroll
    for (int h = 0; h < 8; ++h) acc[h] = 0.f;
    for (int ii = ty; ii < 64; ii += 4) {
        const long idx = (long)(i0 + ii)*NN + j;
        const float dv = dist[idx];
        const float gv = deg[idx];
        const float s0 = fmaf(cb, bond[idx], cg * dv);
        const unsigned short fb = f2b((gv > 0.f) ? s0 : -__builtin_inff());
        fbuf[idx] = fb;
        ddb[idx]  = f2b(-dv * gv);
        const float s = b2f(fb);            // rounded: consistent w/ k3
        #pragma unroll
        for (int h = 0; h < 8; ++h) {
            float r = qs[ii*8 + h] + s;
            r = (r > 0.f) ? r : 0.2f*r;
            acc[h] += __expf(r);            // masked: exp(-inf) = 0
        }
    }
    __shared__ float red[4][64][8];
    #pragma unroll
    for (int h = 0; h < 8; ++h) red[ty][tx][h] = acc[h];
    __syncthreads();
    for (int p = threadIdx.x; p < 512; p += 256) {
        const int jj = p >> 3, h = p & 7;
        const float ssum = red[0][jj][h] + red[1][jj][h] + red[2][jj][h] + red[3][jj][h];
        atomicAdd(&D[(blockIdx.x*64 + jj)*8 + h], ssum);
    }
}

// --------------------------- K3: attn_mean -> bf16 (reads only f-field + qk/D)
__global__ __launch_bounds__(256) void k3_attnmean(
    const unsigned short* __restrict__ fbuf, const float* __restrict__ qk,
    const float* __restrict__ D, unsigned short* __restrict__ amb)
{
    const int tx = threadIdx.x & 63, ty = threadIdx.x >> 6;
    const int j  = blockIdx.x * 64 + tx;
    const int i0 = blockIdx.y * 64;
    __shared__ float qs[64*8];
    for (int p = threadIdx.x; p < 64*8; p += 256) qs[p] = qk[i0*8 + p];
    __syncthreads();
    float invD[8];
    #pragma unroll
    for (int h = 0; h < 8; ++h) invD[h] = 0.125f / fmaxf(D[j*8 + h], 1e-30f);
    for (int ii = ty; ii < 64; ii += 4) {
        const long idx = (long)(i0 + ii)*NN + j;
        const float s = b2f(fbuf[idx]);
        float o = 0.f;
        #pragma unroll
        for (int h = 0; h < 8; ++h) {
            float r = qs[ii*8 + h] + s;
            r = (r > 0.f) ? r : 0.2f*r;
            o = fmaf(__expf(r), invD[h], o);   // masked: exp(-inf)=0 -> o=0
        }
        amb[idx] = f2b(o);
    }
}

// --------------- K4: partial[z] = am_bf(:, z) @ vT_bf(z, :)^T via MFMA
__global__ __launch_bounds__(256) void k4_aggr(
    const unsigned short* __restrict__ amb,
    const unsigned short* __restrict__ vtb, float* __restrict__ partial)
{
    const int i0 = blockIdx.x * 64;
    const int f0 = blockIdx.y * 64;
    const int k0 = blockIdx.z * 512;
    const int w  = threadIdx.x >> 6;
    const int l  = threadIdx.x & 63;
    const int lm = l & 15, lq = l >> 4;
    const int iw = i0 + w*16;
    f32x4 acc[4] = {f32x4{0,0,0,0}, f32x4{0,0,0,0}, f32x4{0,0,0,0}, f32x4{0,0,0,0}};
    for (int kk = k0; kk < k0 + 512; kk += 32) {
        const bhalf8 a = *(const bhalf8*)&amb[(long)(iw + lm)*NN + kk + lq*8];
        #pragma unroll
        for (int c = 0; c < 4; ++c) {
            const bhalf8 b = *(const bhalf8*)&vtb[(long)(f0 + c*16 + lm)*NN + kk + lq*8];
            acc[c] = __builtin_amdgcn_mfma_f32_16x16x32_bf16(a, b, acc[c], 0, 0, 0);
        }
    }
    float* out = partial + (long)blockIdx.z * NN * FOUT;
    #pragma unroll
    for (int c = 0; c < 4; ++c)
        #pragma unroll
        for (int r = 0; r < 4; ++r)
            out[(iw + lq*4 + r)*FOUT + f0 + c*16 + lm] = acc[c][r];
}

// ---------------- K4b: sum 4 partials + elu -> out0 (fp32) + un_bf16
__global__ __launch_bounds__(256) void k4b_elu(
    const float* __restrict__ partial, float* __restrict__ un,
    unsigned short* __restrict__ unb)
{
    const int idx = blockIdx.x*256 + threadIdx.x;
    const float4* p = (const float4*)partial;
    float4 s = p[idx];
    #pragma unroll
    for (int z = 1; z < 4; ++z) {
        const float4 q = p[idx + z*(NN*FOUT/4)];
        s.x += q.x; s.y += q.y; s.z += q.z; s.w += q.w;
    }
    s.x = (s.x > 0.f) ? s.x : (__expf(s.x) - 1.f);
    s.y = (s.y > 0.f) ? s.y : (__expf(s.y) - 1.f);
    s.z = (s.z > 0.f) ? s.z : (__expf(s.z) - 1.f);
    s.w = (s.w > 0.f) ? s.w : (__expf(s.w) - 1.f);
    ((float4*)un)[idx] = s;
    ushort4 ub; ub.x = f2b(s.x); ub.y = f2b(s.y); ub.z = f2b(s.z); ub.w = f2b(s.w);
    *(ushort4*)&unb[(long)idx*4] = ub;
}

// -------- K5: sim = un@un^T via MFMA; c0 = bf16(sigmoid(sim)*ddb); row stats
__global__ __launch_bounds__(256) void k5_sim(
    const unsigned short* __restrict__ unb, const unsigned short* __restrict__ ddb,
    unsigned short* __restrict__ c0,
    float* __restrict__ rowsum, float* __restrict__ rowsq)
{
    const int i0 = blockIdx.y * 64;
    const int j0 = blockIdx.x * 64;
    const int w  = threadIdx.x >> 6;
    const int l  = threadIdx.x & 63;
    const int lm = l & 15, lq = l >> 4;
    const int iw = i0 + w*16;
    f32x4 acc[4] = {f32x4{0,0,0,0}, f32x4{0,0,0,0}, f32x4{0,0,0,0}, f32x4{0,0,0,0}};
    for (int kk = 0; kk < FOUT; kk += 32) {
        const bhalf8 a = *(const bhalf8*)&unb[(long)(iw + lm)*FOUT + kk + lq*8];
        #pragma unroll
        for (int c = 0; c < 4; ++c) {
            const bhalf8 b = *(const bhalf8*)&unb[(long)(j0 + c*16 + lm)*FOUT + kk + lq*8];
            acc[c] = __builtin_amdgcn_mfma_f32_16x16x32_bf16(a, b, acc[c], 0, 0, 0);
        }
    }
    float srow[4] = {0.f,0.f,0.f,0.f}, qrow[4] = {0.f,0.f,0.f,0.f};
    #pragma unroll
    for (int c = 0; c < 4; ++c) {
        #pragma unroll
        for (int r = 0; r < 4; ++r) {
            const int i = iw + lq*4 + r;                 // C/D: row=(l>>4)*4+reg
            const int j = j0 + c*16 + lm;                //      col=l&15
            const long idx = (long)i*NN + j;
            const float sg = 1.f / (1.f + __expf(-acc[c][r]));
            const float val = sg * b2f(ddb[idx]);        // ddb = -dist*deg
            c0[idx] = f2b(val);
            srow[r] += val;
            qrow[r] = fmaf(val, val, qrow[r]);
        }
    }
    #pragma unroll
    for (int r = 0; r < 4; ++r) {
        #pragma unroll
        for (int m = 8; m >= 1; m >>= 1) {
            srow[r] += __shfl_xor(srow[r], m, 64);
            qrow[r] += __shfl_xor(qrow[r], m, 64);
        }
        if (lm == 0) {
            atomicAdd(&rowsum[iw + lq*4 + r], srow[r]);
            atomicAdd(&rowsq[iw + lq*4 + r],  qrow[r]);
        }
    }
}

// ------------------------------------------------------------- K6: mu / rstd
__global__ void k6_stats(const float* __restrict__ rowsum,
                         const float* __restrict__ rowsq,
                         float* __restrict__ mu, float* __restrict__ rs)
{
    const int i = blockIdx.x*256 + threadIdx.x;
    if (i < NN) {
        const float m = rowsum[i] * (1.f/NN);
        const float var = rowsq[i] * (1.f/NN) - m*m;
        mu[i] = m;
        rs[i] = rsqrtf(var + 1e-5f);
    }
}

// ------------------- K7: conn = norm(c0) + norm(c0)^T (c0 bf16 -> fp32 out)
__global__ __launch_bounds__(256) void k7_conn(
    const unsigned short* __restrict__ c0, const float* __restrict__ mu,
    const float* __restrict__ rs, float* __restrict__ out1)
{
    const int i0 = blockIdx.y * 64;
    const int j0 = blockIdx.x * 64;
    const int t  = threadIdx.x;
    __shared__ float LT[64][68];     // LT[i_local][j_local] = c0[j0+jl][i0+il]
    __shared__ float muj[64], rsj[64];
    const int r  = t >> 4;
    const int c4 = (t & 15) * 4;
    if (t < 64)        muj[t] = mu[j0 + t];
    else if (t < 128)  rsj[t-64] = rs[j0 + t - 64];
    #pragma unroll
    for (int p = 0; p < 4; ++p) {
        const int jl = r + p*16;
        const ushort4 q = *(const ushort4*)&c0[(long)(j0 + jl)*NN + i0 + c4];
        LT[c4+0][jl] = b2f(q.x); LT[c4+1][jl] = b2f(q.y);
        LT[c4+2][jl] = b2f(q.z); LT[c4+3][jl] = b2f(q.w);
    }
    __syncthreads();
    #pragma unroll
    for (int p = 0; p < 4; ++p) {
        const int rr = r + p*16;
        const int i  = i0 + rr;
        const ushort4 xb = *(const ushort4*)&c0[(long)i*NN + j0 + c4];
        const float mi = mu[i], ri = rs[i];
        float4 o;
        o.x = (b2f(xb.x) - mi)*ri + (LT[rr][c4+0] - muj[c4+0])*rsj[c4+0];
        o.y = (b2f(xb.y) - mi)*ri + (LT[rr][c4+1] - muj[c4+1])*rsj[c4+1];
        o.z = (b2f(xb.z) - mi)*ri + (LT[rr][c4+2] - muj[c4+2])*rsj[c4+2];
        o.w = (b2f(xb.w) - mi)*ri + (LT[rr][c4+3] - muj[c4+3])*rsj[c4+3];
        *(float4*)&out1[(long)i*NN + j0 + c4] = o;
    }
}

extern "C" void kernel_launch(void* const* d_in, const int* in_sizes, int n_in,
                              void* d_out, int out_size, void* d_ws, size_t ws_size,
                              hipStream_t stream)
{
    // Inputs fp32, outputs fp32 (established rounds 1-5).
    const float* x    = (const float*)d_in[0];
    const float* dist = (const float*)d_in[1];
    const float* bond = (const float*)d_in[2];
    // d_in[3] edge_direction: unused (only l=0 component couples; Y_0 = 1)
    const float* deg  = (const float*)d_in[4];
    const float* Wq   = (const float*)d_in[5];
    const float* Wk   = (const float*)d_in[6];
    const float* Wv   = (const float*)d_in[7];
    const float* wb   = (const float*)d_in[8];
    const float* wbc  = (const float*)d_in[9];
    const float* wg   = (const float*)d_in[10];

    float* out0 = (float*)d_out;            // updated_nodes: 2048*256 fp32
    float* out1 = out0 + (size_t)NN*FOUT;   // conn: 2048*2048 fp32

    // Workspace (~37.9 MB). Lifetime reuse: c0 (bf16, 8.4MB) overlays fbuf
    // (dead after k3). amb dead after k4; ddb dead after k5.
    char* w = (char*)d_ws;
    unsigned short* fbuf = (unsigned short*)(w);              //  8,388,608 B
    unsigned short* c0   = (unsigned short*)(w);              //  8,388,608 B (after k3)
    unsigned short* amb  = (unsigned short*)(w +  8388608);   //  8,388,608 B
    unsigned short* ddb  = (unsigned short*)(w + 16777216);   //  8,388,608 B
    float* partial = (float*)(w + 25165824);                  //  8,388,608 B (4 z)
    float* v       = (float*)(w + 33554432);                  //  2,097,152 B
    unsigned short* vtb = (unsigned short*)(w + 35651584);    //  1,048,576 B
    unsigned short* unb = (unsigned short*)(w + 36700160);    //  1,048,576 B
    float* qk      = (float*)(w + 37748736);                  //     65,536 B
    float* D       = (float*)(w + 37814272);                  //     65,536 B
    float* rowsum  = (float*)(w + 37879808);                  //      8,192 B
    float* rowsq   = (float*)(w + 37888000);                  //      8,192 B
    float* mu      = (float*)(w + 37896192);                  //      8,192 B
    float* rs      = (float*)(w + 37904384);                  //      8,192 B

    hipMemsetAsync(D, 0, 65536 + 8192 + 8192, stream);

    k1_qkv<<<NN/4, 256, 0, stream>>>(x, Wq, Wk, Wv, v, qk);
    dim3 g1b(NN/64, FOUT/64);
    k1b_vT<<<g1b, 256, 0, stream>>>(v, vtb);
    dim3 g23(NN/64, NN/64);
    k2_denom<<<g23, 256, 0, stream>>>(bond, dist, deg, qk, wb, wbc, wg, D, fbuf, ddb);
    k3_attnmean<<<g23, 256, 0, stream>>>(fbuf, qk, D, amb);
    dim3 g4(NN/64, FOUT/64, 4);
    k4_aggr<<<g4, 256, 0, stream>>>(amb, vtb, partial);
    k4b_elu<<<NN*FOUT/4/256, 256, 0, stream>>>(partial, out0, unb);
    dim3 g5(NN/64, NN/64);
    k5_sim<<<g5, 256, 0, stream>>>(unb, ddb, c0, rowsum, rowsq);
    k6_stats<<<8, 256, 0, stream>>>(rowsum, rowsq, mu, rs);
    k7_conn<<<g5, 256, 0, stream>>>(c0, mu, rs, out1);
}